// Round 5
// baseline (579.182 us; speedup 1.0000x reference)
//
#include <hip/hip_runtime.h>

// ---- types ----
typedef _Float16 f16;
typedef _Float16 f16x8 __attribute__((ext_vector_type(8)));
typedef _Float16 f16x4 __attribute__((ext_vector_type(4)));
typedef __fp16   h16x2 __attribute__((ext_vector_type(2)));   // cvt_pkrtz ret type
typedef float    f32x4 __attribute__((ext_vector_type(4)));

// ---- problem constants ----
constexpr int NB   = 8;      // batch
constexpr int T    = 2048;   // Tx = Tz
constexpr int D    = 1024;   // Dx = Dz = Datt = Dout
constexpr int NTRI = 136;    // 16*17/2 causal 128x128 blocks per batch

// async global->LDS, 16B per lane; LDS dest = wave-uniform base + lane*16
__device__ __forceinline__ void load_lds16(const void* g, void* l) {
    __builtin_amdgcn_global_load_lds(
        (const __attribute__((address_space(1))) void*)g,
        (__attribute__((address_space(3))) void*)l, 16, 0, 0);
}

// =====================================================================
// Weight cast + transpose: W[k][n] fp32 -> Wt[n][k] f16   (3 matrices,
// concatenated: [Wq^T | Wk^T | Wv^T], 3*1024*1024 f16)
// =====================================================================
__global__ __launch_bounds__(256) void cast_transpose_w(
    const float* __restrict__ W0, const float* __restrict__ W1,
    const float* __restrict__ W2, f16* __restrict__ Wt)
{
    __shared__ f16 tile[32][33];
    const int which = blockIdx.z;
    const float* W = which == 0 ? W0 : (which == 1 ? W1 : W2);
    f16* dst = Wt + (size_t)which * D * D;
    const int c0 = blockIdx.x * 32, r0 = blockIdx.y * 32;
    const int tx = threadIdx.x & 31, ty = threadIdx.x >> 5;
    #pragma unroll
    for (int i = 0; i < 32; i += 8)
        tile[ty + i][tx] = (f16)W[(size_t)(r0 + ty + i) * D + c0 + tx];
    __syncthreads();
    #pragma unroll
    for (int i = 0; i < 32; i += 8)
        dst[(size_t)(c0 + ty + i) * D + r0 + tx] = tile[tx][ty + i];
}

// =====================================================================
// Fused QKV projection GEMM, 128x128 tile, BK=32, 256 threads.
// A = x (bx<8) or z (bx>=8), fp32, cast->f16 at fragment build
// (fp32 staged in LDS with XOR-chunk swizzle to kill 32-bank aliasing).
// B = Wt = [Wq|Wk|Wv]^T f16. Epilogue: bx<8 -> Qh f16; 8<=bx<16 -> Kh f16;
// bx>=16 -> Vt f16 written TRANSPOSED per batch [b][o][t].
// =====================================================================
__global__ __launch_bounds__(256) void gemm_qkv(
    const float* __restrict__ xg, const float* __restrict__ zg,
    const f16* __restrict__ Wt,
    f16* __restrict__ Qh, f16* __restrict__ Kh, f16* __restrict__ Vt,
    const float* __restrict__ bq, const float* __restrict__ bk,
    const float* __restrict__ bv)
{
    __shared__ __align__(16) float As32[128 * 32];   // 16 KB, swizzled chunks
    __shared__ __align__(16) f16   Bs[128 * 32];     //  8 KB

    const int bx = blockIdx.x, by = blockIdx.y;
    const size_t bm0 = (size_t)by * 128, bn0 = (size_t)bx * 128;
    const float* Ag = (bx < 8) ? xg : zg;
    const f16*   Bg = Wt + bn0 * D;

    const int t    = threadIdx.x;
    const int lane = t & 63, wave = t >> 6;
    const int wr   = (wave >> 1) * 64, wc = (wave & 1) * 64;
    const int fr   = lane & 15, fo = (lane >> 4) * 8;
    // f16 B staging: row = t>>2, col chunk = (t&3)*8, wave base = (t&192)*8
    const int srow16 = t >> 2, scol16 = (t & 3) * 8, wub16 = (t & 192) * 8;
    // fp32 A staging: per it, wave covers 8 rows; XOR swizzle on chunk
    const int arow = (lane >> 3);                     // 0..7 within wave block
    const int acol = (((lane & 7) ^ arow) << 2);      // swizzled float col

    f32x4 acc[4][4] = {};

    for (int k0 = 0; k0 < D; k0 += 32) {
        #pragma unroll
        for (int it = 0; it < 4; ++it)
            load_lds16(Ag + (bm0 + it * 32 + wave * 8 + arow) * D + k0 + acol,
                       As32 + it * 1024 + wave * 256);
        #pragma unroll
        for (int it = 0; it < 2; ++it)
            load_lds16(Bg + k0 + (size_t)(it * 64 + srow16) * D + scol16,
                       Bs + it * 2048 + wub16);
        __syncthreads();

        f16x8 av[4], bvv[4];
        #pragma unroll
        for (int i = 0; i < 4; ++i) {
            const int rA = wr + i * 16 + fr;
            const int sw = rA & 7;
            const float* Ra = As32 + rA * 32;
            const float4 lo = *(const float4*)(Ra + ((((fo >> 2) + 0) ^ sw) << 2));
            const float4 hi = *(const float4*)(Ra + ((((fo >> 2) + 1) ^ sw) << 2));
            union { f16x8 v; h16x2 h[4]; } u;
            u.h[0] = __builtin_amdgcn_cvt_pkrtz(lo.x, lo.y);
            u.h[1] = __builtin_amdgcn_cvt_pkrtz(lo.z, lo.w);
            u.h[2] = __builtin_amdgcn_cvt_pkrtz(hi.x, hi.y);
            u.h[3] = __builtin_amdgcn_cvt_pkrtz(hi.z, hi.w);
            av[i] = u.v;
        }
        #pragma unroll
        for (int j = 0; j < 4; ++j)
            bvv[j] = *(const f16x8*)&Bs[(wc + j * 16 + fr) * 32 + fo];
        #pragma unroll
        for (int i = 0; i < 4; ++i)
            #pragma unroll
            for (int j = 0; j < 4; ++j)
                acc[i][j] = __builtin_amdgcn_mfma_f32_16x16x32_f16(av[i], bvv[j], acc[i][j], 0, 0, 0);
        __syncthreads();
    }

    // ---- epilogue.  C/D map: col = lane&15, row = (lane>>4)*4 + reg ----
    const int cr = (lane >> 4) * 4, cc = lane & 15;
    const int grp = bx >> 3;                 // 0=Q, 1=K, 2=V
    if (grp < 2) {
        f16* Cp = grp == 0 ? Qh : Kh;
        const float* bias = grp == 0 ? bq : bk;
        #pragma unroll
        for (int j = 0; j < 4; ++j) {
            const int col = (int)bn0 - grp * 1024 + wc + j * 16 + cc;
            const float bb = bias[col];
            #pragma unroll
            for (int i = 0; i < 4; ++i)
                #pragma unroll
                for (int g = 0; g < 4; ++g)
                    Cp[(bm0 + wr + i * 16 + cr + g) * D + col] = (f16)(acc[i][j][g] + bb);
        }
    } else {
        const int b  = (int)(bm0 >> 11);
        const int r0 = (int)(bm0 & 2047);
        #pragma unroll
        for (int j = 0; j < 4; ++j) {
            const int colv = (int)bn0 - 2048 + wc + j * 16 + cc;
            const float bb = bv[colv];
            #pragma unroll
            for (int i = 0; i < 4; ++i) {
                f16x4 pk = { (f16)(acc[i][j][0] + bb), (f16)(acc[i][j][1] + bb),
                             (f16)(acc[i][j][2] + bb), (f16)(acc[i][j][3] + bb) };
                *(f16x4*)&Vt[(size_t)b * D * T + (size_t)colv * T + r0 + wr + i * 16 + cr] = pk;
            }
        }
    }
}

// =====================================================================
// Attention GEMMs, 128x128 tile, BK=32, 256 threads, f16 staging.
// MODE 1: S    A=Qh[b], B=Kh[b]; triangular grid; writes UNNORMALIZED
//              p=exp(S/32) f16 packed causal blocks (masked->0) + fp32
//              row sums via atomics into rsum
// MODE 2: y    A=packed p, B=Vt[b]; K clipped causal, by descending;
//              epilogue scales by 1/rsum; C fp32
// =====================================================================
template<int MODE>
__global__ __launch_bounds__(256) void gemm_attn(
    const f16* __restrict__ Ag_, const f16* __restrict__ Bg_,
    void* __restrict__ Cg_, float* __restrict__ rsum)
{
    __shared__ __align__(16) f16 As[128 * 32];
    __shared__ __align__(16) f16 Bs[128 * 32];

    int bx, by;
    const int bz = blockIdx.z;
    if (MODE == 1) {
        const int idx = blockIdx.x;
        by = (int)((sqrtf(8.0f * idx + 1.0f) - 1.0f) * 0.5f);
        while ((by + 1) * (by + 2) / 2 <= idx) ++by;
        while (by * (by + 1) / 2 > idx) --by;
        bx = idx - by * (by + 1) / 2;
    } else {
        bx = blockIdx.x; by = 15 - blockIdx.y;   // long-K blocks first
    }

    const size_t bm0 = (size_t)by * 128, bn0 = (size_t)bx * 128;
    const f16* Abase; const f16* Bbase;
    int lda, ldb, K;
    if (MODE == 1) {
        Abase = Ag_ + (size_t)bz * T * D + bm0 * D;  lda = D;
        Bbase = Bg_ + (size_t)bz * T * D + bn0 * D;  ldb = D; K = D;
    } else {
        Abase = Ag_ + ((size_t)bz * NTRI + (size_t)by * (by + 1) / 2) * 16384;
        lda = 128;
        Bbase = Bg_ + (size_t)bz * D * T + bn0 * T;  ldb = T;
        K = (by + 1) * 128;
    }

    const int t    = threadIdx.x;
    const int lane = t & 63, wave = t >> 6;
    const int wr   = (wave >> 1) * 64, wc = (wave & 1) * 64;
    const int fr   = lane & 15, fo = (lane >> 4) * 8;
    const int srow = t >> 2, scol = (t & 3) * 8, wub = (t & 192) * 8;

    f32x4 acc[4][4] = {};

    for (int k0 = 0; k0 < K; k0 += 32) {
        const f16* Ak;
        if (MODE == 2) Ak = Abase + (size_t)(k0 >> 7) * 16384 + (k0 & 127);
        else           Ak = Abase + k0;
        #pragma unroll
        for (int it = 0; it < 2; ++it)
            load_lds16(Ak + (size_t)(it * 64 + srow) * lda + scol,
                       As + it * 2048 + wub);
        #pragma unroll
        for (int it = 0; it < 2; ++it)
            load_lds16(Bbase + k0 + (size_t)(it * 64 + srow) * ldb + scol,
                       Bs + it * 2048 + wub);
        __syncthreads();

        f16x8 av[4], bvv[4];
        #pragma unroll
        for (int i = 0; i < 4; ++i)
            av[i] = *(const f16x8*)&As[(wr + i * 16 + fr) * 32 + fo];
        #pragma unroll
        for (int j = 0; j < 4; ++j)
            bvv[j] = *(const f16x8*)&Bs[(wc + j * 16 + fr) * 32 + fo];
        #pragma unroll
        for (int i = 0; i < 4; ++i)
            #pragma unroll
            for (int j = 0; j < 4; ++j)
                acc[i][j] = __builtin_amdgcn_mfma_f32_16x16x32_f16(av[i], bvv[j], acc[i][j], 0, 0, 0);
        __syncthreads();
    }

    // ---- epilogue.  C/D map: col = lane&15, row = (lane>>4)*4 + reg ----
    const int cr = (lane >> 4) * 4, cc = lane & 15;
    if (MODE == 1) {
        f16* Cp = (f16*)Cg_ + ((size_t)bz * NTRI + (size_t)by * (by + 1) / 2 + bx) * 16384;
        float* rs = rsum + (size_t)bz * T + bm0;
        float rowsum[4][4] = {};   // [i][g]
        #pragma unroll
        for (int i = 0; i < 4; ++i)
            #pragma unroll
            for (int j = 0; j < 4; ++j)
                #pragma unroll
                for (int g = 0; g < 4; ++g) {
                    const int lr = wr + i * 16 + cr + g, lc = wc + j * 16 + cc;
                    const int r = (int)bm0 + lr, c = (int)bn0 + lc;
                    const float p = (c > r) ? 0.0f : __expf(acc[i][j][g] * 0.03125f);
                    Cp[lr * 128 + lc] = (f16)p;
                    rowsum[i][g] += p;
                }
        #pragma unroll
        for (int i = 0; i < 4; ++i)
            #pragma unroll
            for (int g = 0; g < 4; ++g) {
                float s = rowsum[i][g];
                s += __shfl_xor(s, 1, 64);
                s += __shfl_xor(s, 2, 64);
                s += __shfl_xor(s, 4, 64);
                s += __shfl_xor(s, 8, 64);
                if (cc == 0) atomicAdd(&rs[wr + i * 16 + cr + g], s);
            }
    } else {
        float* Cp = (float*)Cg_ + (size_t)bz * T * D;
        const float* rs = rsum + (size_t)bz * T;
        #pragma unroll
        for (int i = 0; i < 4; ++i) {
            const int r4 = (int)bm0 + wr + i * 16 + cr;
            float rinv[4];
            #pragma unroll
            for (int g = 0; g < 4; ++g) rinv[g] = 1.0f / rs[r4 + g];
            #pragma unroll
            for (int j = 0; j < 4; ++j)
                #pragma unroll
                for (int g = 0; g < 4; ++g)
                    Cp[(size_t)(r4 + g) * D + bn0 + wc + j * 16 + cc] = acc[i][j][g] * rinv[g];
        }
    }
}

// =====================================================================
// launch
// =====================================================================
extern "C" void kernel_launch(void* const* d_in, const int* in_sizes, int n_in,
                              void* d_out, int out_size, void* d_ws, size_t ws_size,
                              hipStream_t stream)
{
    const float* x  = (const float*)d_in[0];
    const float* z  = (const float*)d_in[1];
    const float* Wq = (const float*)d_in[2];
    const float* bq = (const float*)d_in[3];
    const float* Wk = (const float*)d_in[4];
    const float* bk = (const float*)d_in[5];
    const float* Wv = (const float*)d_in[6];
    const float* bv = (const float*)d_in[7];
    // d_in[8] = mask: fixed causal lower-triangular, baked in.
    float* out = (float*)d_out;

    char* ws = (char*)d_ws;
    // ws layout: Wt 6 MiB | Qh 32 | Kh 32 | Vt 32 | SA 34 | rsum 64 KiB
    f16*   Wt   = (f16*)(ws);
    f16*   Qh   = (f16*)(ws + 6291456ull);
    f16*   Kh   = (f16*)(ws + 39845888ull);
    f16*   Vt   = (f16*)(ws + 73400320ull);
    f16*   SA   = (f16*)(ws + 106954752ull);
    float* rsum = (float*)(ws + 142606336ull);

    (void)hipMemsetAsync(rsum, 0, (size_t)NB * T * sizeof(float), stream);
    cast_transpose_w<<<dim3(32, 32, 3), 256, 0, stream>>>(Wq, Wk, Wv, Wt);
    gemm_qkv<<<dim3(24, 128, 1), 256, 0, stream>>>(x, z, Wt, Qh, Kh, Vt, bq, bk, bv);
    gemm_attn<1><<<dim3(136, 1, 8), 256, 0, stream>>>(Qh, Kh, SA, rsum);
    gemm_attn<2><<<dim3(8, 16, 8), 256, 0, stream>>>(SA, Vt, out, rsum);
}